// Round 8
// baseline (685.259 us; speedup 1.0000x reference)
//
#include <hip/hip_runtime.h>
#include <stdint.h>

// Problem constants
#define Bb  8
#define Ss  4096
#define Dd  512
#define DIi 2048
#define Mm  (Bb*Ss)   // 32768 rows

typedef unsigned short u16;
typedef __bf16 bf16x8 __attribute__((ext_vector_type(8)));
typedef float  f32x4  __attribute__((ext_vector_type(4)));

__device__ __forceinline__ float bfu(unsigned int u) {
  return __uint_as_float((u & 0xffffu) << 16);
}
__device__ __forceinline__ u16 f2bu(float f) {
  unsigned int x = __float_as_uint(f);
  return (u16)((x + 0x7fffu + ((x >> 16) & 1u)) >> 16);  // RNE
}

// XCD-chunk remap: 8-panel row-chunks per XCD. Requires gridDim.y % 64 == 0.
__device__ __forceinline__ void xcd_remap(int& bx, int& by) {
  const int nx = gridDim.x;
  const int s = by * nx + bx;
  const int xcd = s & 7;
  const int g = s >> 3;
  const int cpc = nx << 3;
  const int cw = g / cpc;
  const int rem = g % cpc;
  by = cw * 64 + xcd * 8 + rem / nx;
  bx = rem % nx;
}

__global__ __launch_bounds__(256) void zero_f32(float* __restrict__ p, int n) {
  int i = blockIdx.x * 256 + threadIdx.x;
  if (i < n) p[i] = 0.f;
}

__global__ __launch_bounds__(256) void f32_to_bf16_vec(const float* __restrict__ in,
                                                       u16* __restrict__ outp, long n4) {
  long i = (long)blockIdx.x * 256 + threadIdx.x;
  const long st = (long)gridDim.x * 256;
  for (; i < n4; i += st) {
    float4 v = ((const float4*)in)[i];
    ushort4 o;
    o.x = f2bu(v.x); o.y = f2bu(v.y); o.z = f2bu(v.z); o.w = f2bu(v.w);
    ((ushort4*)outp)[i] = o;
  }
}

// batched transpose f32 [K][N] -> bf16 [N][K]; blockIdx.z selects the pair
__global__ void transpose_f32_bf16_z(const float* s0, const float* s1,
                                     const float* s2, const float* s3,
                                     u16* d0, u16* d1, u16* d2, u16* d3,
                                     int K, int N) {
  const float* W; u16* Wt;
  switch (blockIdx.z) {
    case 0:  W = s0; Wt = d0; break;
    case 1:  W = s1; Wt = d1; break;
    case 2:  W = s2; Wt = d2; break;
    default: W = s3; Wt = d3; break;
  }
  __shared__ float t[32][33];
  const int n0 = blockIdx.x * 32, k0 = blockIdx.y * 32;
  const int tx = threadIdx.x, ty = threadIdx.y;  // 32 x 8
#pragma unroll
  for (int i = 0; i < 32; i += 8)
    t[ty + i][tx] = W[(long)(k0 + ty + i) * N + n0 + tx];
  __syncthreads();
#pragma unroll
  for (int i = 0; i < 32; i += 8)
    Wt[(long)(n0 + ty + i) * K + k0 + tx] = f2bu(t[tx][ty + i]);
}

// wob[b][n][k] = woT[n][k] * kv[b][k]   (bf16 out, 8 batch copies of wo^T)
__global__ __launch_bounds__(256) void build_wob(const u16* __restrict__ woT,
                                                 const float* __restrict__ kv,
                                                 u16* __restrict__ wob) {
  const int b = blockIdx.y;
  long i = (long)blockIdx.x * 256 + threadIdx.x;
  const long tot = (long)Dd * DIi / 8;
  if (i >= tot) return;
  const long e = i * 8;
  const int k = (int)(e & (DIi - 1));
  ushort4 w0 = *(const ushort4*)(woT + e);
  ushort4 w1 = *(const ushort4*)(woT + e + 4);
  const float* kvp = kv + (long)b * DIi + k;
  ushort4 o0, o1;
  o0.x = f2bu(bfu(w0.x) * kvp[0]); o0.y = f2bu(bfu(w0.y) * kvp[1]);
  o0.z = f2bu(bfu(w0.z) * kvp[2]); o0.w = f2bu(bfu(w0.w) * kvp[3]);
  o1.x = f2bu(bfu(w1.x) * kvp[4]); o1.y = f2bu(bfu(w1.y) * kvp[5]);
  o1.z = f2bu(bfu(w1.z) * kvp[6]); o1.w = f2bu(bfu(w1.w) * kvp[7]);
  u16* dst = wob + (long)b * Dd * DIi + e;
  *(ushort4*)dst = o0;
  *(ushort4*)(dst + 4) = o1;
}

// kv[b,e] = sum_s P[b,s,e] * rsqrt(nksq[b,s])   (f32 atomics over s-chunks)
__global__ __launch_bounds__(256) void kv_reduce(const u16* __restrict__ P,
                                                 const float* __restrict__ nksq,
                                                 float* __restrict__ kv) {
  const int b  = blockIdx.y;
  const int e0 = blockIdx.x * 1024 + threadIdx.x * 4;
  const int s0 = blockIdx.z * 256;
  const u16* pp = P + ((size_t)(b * Ss + s0)) * DIi + e0;
  const float* nn = nksq + b * Ss + s0;
  float a0 = 0, a1 = 0, a2 = 0, a3 = 0;
  for (int s = 0; s < 256; ++s) {
    const float r = 1.f / fmaxf(sqrtf(nn[s]), 1e-12f);
    ushort4 u = *(const ushort4*)pp;
    a0 += bfu(u.x) * r;
    a1 += bfu(u.y) * r;
    a2 += bfu(u.z) * r;
    a3 += bfu(u.w) * r;
    pp += DIi;
  }
  float* o = kv + (long)b * DIi + e0;
  atomicAdd(o + 0, a0); atomicAdd(o + 1, a1);
  atomicAdd(o + 2, a2); atomicAdd(o + 3, a3);
}

#define GLL(src, dst) \
  __builtin_amdgcn_global_load_lds((const __attribute__((address_space(1))) unsigned int*)(src), \
                                   (__attribute__((address_space(3))) unsigned int*)(dst), 16, 0, 0)

// ===== fused K,V product GEMM v3: all staging at tile boundary =====
// acc1 = x@wk tile, acc2 = x@wv tile; P = bf16(acc1*acc2); nksq += acc1^2.
// Tile t+2 staged in one burst at tile-t boundary -> vmcnt(5) waits on loads
// aged one full tile (2 MFMA phases) -> near-zero drain stall.
__global__ __launch_bounds__(512, 2) void kvp_gemm(
    const u16* __restrict__ A, const u16* __restrict__ B1, const u16* __restrict__ B2,
    u16* __restrict__ P, float* __restrict__ nksq)
{
  __shared__ u16 lds8[40960];   // 80 KB
  const int K = Dd, N = DIi;

  int bx = blockIdx.x, by = blockIdx.y;
  xcd_remap(bx, by);
  const int tid = threadIdx.x, lane = tid & 63, wid = tid >> 6;
  const int wr = wid >> 2, wc = wid & 3;     // 2x4 wave grid; wave tile 64x64
  const int l15 = lane & 15, lg = lane >> 4;
  const long bm0 = (long)by * 128, bn0 = (long)bx * 256;
  const int NT = K >> 5;                     // 16 K-tiles of 32

  const u16* pA  = A  + bm0 * K;
  const u16* pB1 = B1 + bn0 * K;
  const u16* pB2 = B2 + bn0 * K;

  const int qrow = ((tid >> 5) << 3) | (tid & 7);   // 0..127
  const int qcol = ((tid >> 3) & 3) * 8;            // 0,8,16,24

#define STAGEA(TT, BUFB) do {                                               \
    const u16* s_ = pA + (size_t)qrow * K + (TT) * 32 + qcol;               \
    GLL(s_, (u16*)((char*)lds8 + (BUFB) + tid * 16));                       \
  } while (0)
#define STAGEB(PTR, TT, QB, BUFB) do {                                      \
    const u16* s_ = (PTR) + (size_t)qrow * K + (TT) * 32 + qcol;            \
    u16* d_ = (u16*)((char*)lds8 + (BUFB) + (QB) + tid * 16);               \
    GLL(s_, d_);                                                            \
    GLL(s_ + (size_t)128 * K, (u16*)((char*)d_ + 8192));                    \
  } while (0)

  const int fb = (l15 >> 3) * 512 + lg * 128 + (l15 & 7) * 16;
  const int abyte  = wr * 4096 + fb;
  const int b1byte = 8192 + wc * 4096 + fb;
  const int b2byte = 24576 + wc * 4096 + fb;

  f32x4 acc1[4][4] = {};
  f32x4 acc2[4][4] = {};

  // prologue: full tile0 + full tile1 (5 GLL each), wait tile0 only
  STAGEA(0, 0);
  STAGEB(pB1, 0, 8192, 0);
  STAGEB(pB2, 0, 24576, 0);
  STAGEA(1, 40960);
  STAGEB(pB1, 1, 8192, 40960);
  STAGEB(pB2, 1, 24576, 40960);
  asm volatile("s_waitcnt vmcnt(5)" ::: "memory");
  __builtin_amdgcn_s_barrier();

  for (int t = 0; t < NT; ++t) {
    const int bufb = (t & 1) * 40960;
    bf16x8 aF[4], bF[4];

    // ---- phase 0: A + B1 frags; mfma acc1 ----
#pragma unroll
    for (int m = 0; m < 4; ++m)
      aF[m] = *(const bf16x8*)((const char*)lds8 + bufb + abyte + m * 1024);
#pragma unroll
    for (int n = 0; n < 4; ++n)
      bF[n] = *(const bf16x8*)((const char*)lds8 + bufb + b1byte + n * 1024);
    __builtin_amdgcn_s_barrier();
    __builtin_amdgcn_s_setprio(1);
#pragma unroll
    for (int m = 0; m < 4; ++m)
#pragma unroll
      for (int n = 0; n < 4; ++n)
        acc1[m][n] = __builtin_amdgcn_mfma_f32_16x16x32_bf16(aF[m], bF[n], acc1[m][n], 0, 0, 0);
    __builtin_amdgcn_s_setprio(0);

    // ---- phase 1: B2 frags; mfma acc2 ----
#pragma unroll
    for (int n = 0; n < 4; ++n)
      bF[n] = *(const bf16x8*)((const char*)lds8 + bufb + b2byte + n * 1024);
    __builtin_amdgcn_s_barrier();
    __builtin_amdgcn_s_setprio(1);
#pragma unroll
    for (int m = 0; m < 4; ++m)
#pragma unroll
      for (int n = 0; n < 4; ++n)
        acc2[m][n] = __builtin_amdgcn_mfma_f32_16x16x32_bf16(aF[m], bF[n], acc2[m][n], 0, 0, 0);
    __builtin_amdgcn_s_setprio(0);

    // ---- tile boundary: stage full t+2 into freed buffer; drain t+1 ----
    if (t + 1 < NT) {
      __builtin_amdgcn_s_barrier();            // all reads of bufb done
      if (t + 2 < NT) {
        STAGEA(t + 2, bufb);
        STAGEB(pB1, t + 2, 8192, bufb);
        STAGEB(pB2, t + 2, 24576, bufb);
        asm volatile("s_waitcnt vmcnt(5)" ::: "memory");   // t+1's 5 retire
      } else {
        asm volatile("s_waitcnt vmcnt(0)" ::: "memory");
      }
      __builtin_amdgcn_s_barrier();            // t+1 buffer visible
    }
  }

  // epilogue: P = bf16(k*v), nksq += k^2 (per-row)
  float sk[16];
#pragma unroll
  for (int i = 0; i < 16; ++i) sk[i] = 0.f;
#pragma unroll
  for (int m = 0; m < 4; ++m) {
    const long row0 = bm0 + wr * 64 + m * 16 + lg * 4;
#pragma unroll
    for (int n = 0; n < 4; ++n) {
      const long col = bn0 + wc * 64 + n * 16 + l15;
#pragma unroll
      for (int r = 0; r < 4; ++r) {
        const float kvl = acc1[m][n][r];
        P[(row0 + r) * N + col] = f2bu(kvl * acc2[m][n][r]);
        sk[m * 4 + r] += kvl * kvl;
      }
    }
  }
#pragma unroll
  for (int i = 0; i < 16; ++i) {
#pragma unroll
    for (int off = 1; off < 16; off <<= 1)
      sk[i] += __shfl_xor(sk[i], off, 64);
  }
  if (l15 == 0) {
#pragma unroll
    for (int m = 0; m < 4; ++m)
#pragma unroll
      for (int r = 0; r < 4; ++r)
        atomicAdd(&nksq[bm0 + wr * 64 + m * 16 + lg * 4 + r], sk[m * 4 + r]);
  }
#undef STAGEA
#undef STAGEB
}

// ===== 256^2-tile 8-wave GEMM v2: all staging at tile boundary =====
enum { G_PROJ = 0, G_WO = 1, G_FFN1 = 2, G_FFN2 = 3 };

template<int MODE>
__global__ __launch_bounds__(512, 2) void gemm8(
    const u16* __restrict__ A, const u16* __restrict__ Bt,
    int N, int K,
    u16* __restrict__ Ybf, float* __restrict__ Yf,
    const u16* __restrict__ resb, const float* __restrict__ bias,
    float* __restrict__ nsq, const float* __restrict__ nsqIn)
{
  __shared__ u16 lds8[65536];   // 128 KB

  int bx = blockIdx.x, by = blockIdx.y;
  xcd_remap(bx, by);
  const int tid  = threadIdx.x;
  const int lane = tid & 63;
  const int wid  = tid >> 6;
  const int wr = wid >> 2, wc = wid & 3;
  const int l15 = lane & 15, lg = lane >> 4;
  const long bm0 = (long)by * 256;
  const long bn0 = (long)bx * 256;
  const int NT = K >> 6;

  const int bq = (int)(bm0 >> 12);
  const u16* pA = A + bm0 * K;
  const u16* pB = Bt + bn0 * K + (MODE == G_WO ? (size_t)bq * Dd * DIi : 0);

  const int rowT = ((tid >> 6) << 3) | (tid & 7);
  const int cc8  = ((tid >> 3) & 7) * 8;

#define STAGE(PTR, LD, H, TT, BUFU, REGU) do {                                  \
    const u16* s0_ = (PTR) + (size_t)((H) * 128 + rowT) * (LD)                  \
                     + (size_t)(TT) * 64 + cc8;                                 \
    u16* d_ = lds8 + (BUFU) + (REGU) + (H) * 8192 + wid * 512;                  \
    GLL(s0_, d_);                                                               \
    GLL(s0_ + (size_t)64 * (LD), d_ + 4096);                                    \
  } while (0)
#define STAGET(TT, BUFU) do {                                                   \
    STAGE(pA, K, 0, TT, BUFU, 0);                                               \
    STAGE(pA, K, 1, TT, BUFU, 0);                                               \
    STAGE(pB, K, 0, TT, BUFU, 16384);                                           \
    STAGE(pB, K, 1, TT, BUFU, 16384);                                           \
  } while (0)

  const int aoff = (wr * 16384 + (l15 >> 3) * 1024 + lg * 128 + (l15 & 7) * 16) >> 1;
  const int boff = (32768 + (wc >> 1) * 16384 + (wc & 1) * 8192 +
                    (l15 >> 3) * 1024 + lg * 128 + (l15 & 7) * 16) >> 1;
#define LDA(M_, KS_, BU_) (*(const bf16x8*)(lds8 + (BU_) + aoff + (M_) * 1024 + (KS_) * 256))
#define LDB(N_, KS_, BU_) (*(const bf16x8*)(lds8 + (BU_) + boff + (N_) * 1024 + (KS_) * 256))

  f32x4 acc[8][4] = {};

  // prologue: full tile0 + full tile1 (8 GLL each); wait tile0 only
  STAGET(0, 0);
  STAGET(1, 32768);
  asm volatile("s_waitcnt vmcnt(8)" ::: "memory");
  __builtin_amdgcn_s_barrier();

  for (int t = 0; t < NT; ++t) {
    const int bufu = (t & 1) * 32768;
    bf16x8 aF[4], bF[4];

    // ---- phase 0: B ks0 + A(m0-3) ks0 ----
#pragma unroll
    for (int n = 0; n < 4; ++n) bF[n] = LDB(n, 0, bufu);
#pragma unroll
    for (int m = 0; m < 4; ++m) aF[m] = LDA(m, 0, bufu);
    __builtin_amdgcn_s_barrier();
    __builtin_amdgcn_s_setprio(1);
#pragma unroll
    for (int m = 0; m < 4; ++m)
#pragma unroll
      for (int n = 0; n < 4; ++n)
        acc[m][n] = __builtin_amdgcn_mfma_f32_16x16x32_bf16(aF[m], bF[n], acc[m][n], 0, 0, 0);
    __builtin_amdgcn_s_setprio(0);

    // ---- phase 1: A(m4-7) ks0 ----
#pragma unroll
    for (int m = 0; m < 4; ++m) aF[m] = LDA(4 + m, 0, bufu);
    __builtin_amdgcn_s_barrier();
    __builtin_amdgcn_s_setprio(1);
#pragma unroll
    for (int m = 0; m < 4; ++m)
#pragma unroll
      for (int n = 0; n < 4; ++n)
        acc[4 + m][n] = __builtin_amdgcn_mfma_f32_16x16x32_bf16(aF[m], bF[n], acc[4 + m][n], 0, 0, 0);
    __builtin_amdgcn_s_setprio(0);

    // ---- phase 2: B ks1 + A(m0-3) ks1 ----
#pragma unroll
    for (int n = 0; n < 4; ++n) bF[n] = LDB(n, 1, bufu);
#pragma unroll
    for (int m = 0; m < 4; ++m) aF[m] = LDA(m, 1, bufu);
    __builtin_amdgcn_s_barrier();
    __builtin_amdgcn_s_setprio(1);
#pragma unroll
    for (int m = 0; m < 4; ++m)
#pragma unroll
      for (int n = 0; n < 4; ++n)
        acc[m][n] = __builtin_amdgcn_mfma_f32_16x16x32_bf16(aF[m], bF[n], acc[m][n], 0, 0, 0);
    __builtin_amdgcn_s_setprio(0);

    // ---- phase 3: A(m4-7) ks1 ----
#pragma unroll
    for (int m = 0; m < 4; ++m) aF[m] = LDA(4 + m, 1, bufu);
    __builtin_amdgcn_s_barrier();
    __builtin_amdgcn_s_setprio(1);
#pragma unroll
    for (int m = 0; m < 4; ++m)
#pragma unroll
      for (int n = 0; n < 4; ++n)
        acc[4 + m][n] = __builtin_amdgcn_mfma_f32_16x16x32_bf16(aF[m], bF[n], acc[4 + m][n], 0, 0, 0);
    __builtin_amdgcn_s_setprio(0);

    // ---- tile boundary: stage full t+2 into freed buffer; drain t+1 ----
    if (t + 1 < NT) {
      __builtin_amdgcn_s_barrier();            // all reads of bufu done
      if (t + 2 < NT) {
        STAGET(t + 2, bufu);
        asm volatile("s_waitcnt vmcnt(8)" ::: "memory");   // t+1's 8 retire
      } else {
        asm volatile("s_waitcnt vmcnt(0)" ::: "memory");
      }
      __builtin_amdgcn_s_barrier();            // t+1 buffer visible
    }
  }

  // =================== epilogue ===================
  if constexpr (MODE == G_PROJ) {
    float sk[32];
#pragma unroll
    for (int i = 0; i < 32; ++i) sk[i] = 0.f;
#pragma unroll
    for (int m = 0; m < 8; ++m) {
      const long row0 = bm0 + wr * 128 + m * 16 + lg * 4;
#pragma unroll
      for (int n = 0; n < 4; ++n) {
        const long col = bn0 + wc * 64 + n * 16 + l15;
#pragma unroll
        for (int r = 0; r < 4; ++r) {
          const float v = acc[m][n][r];
          Ybf[(row0 + r) * N + col] = f2bu(v);
          sk[m * 4 + r] += v * v;
        }
      }
    }
#pragma unroll
    for (int i = 0; i < 32; ++i) {
#pragma unroll
      for (int off = 1; off < 16; off <<= 1)
        sk[i] += __shfl_xor(sk[i], off, 64);
    }
    if (l15 == 0) {
#pragma unroll
      for (int m = 0; m < 8; ++m)
#pragma unroll
        for (int r = 0; r < 4; ++r)
          atomicAdd(&nsq[bm0 + wr * 128 + m * 16 + lg * 4 + r], sk[m * 4 + r]);
    }
  } else {
#pragma unroll
    for (int m = 0; m < 8; ++m) {
      const long row0 = bm0 + wr * 128 + m * 16 + lg * 4;
      float rq[4];
      if constexpr (MODE == G_WO) {
#pragma unroll
        for (int r = 0; r < 4; ++r)
          rq[r] = 1.f / fmaxf(sqrtf(nsqIn[row0 + r]), 1e-12f);
      }
#pragma unroll
      for (int n = 0; n < 4; ++n) {
        const long col = bn0 + wc * 64 + n * 16 + l15;
#pragma unroll
        for (int r = 0; r < 4; ++r) {
          const long idx = (row0 + r) * N + col;
          const float v = acc[m][n][r];
          if constexpr (MODE == G_WO) {
            Ybf[idx] = f2bu(v * rq[r] + bfu(resb[idx]));   // resb == Ybf, same idx
          } else if constexpr (MODE == G_FFN1) {
            float o = v + bias[col];
            o = o > 0.f ? o : 0.f;
            Ybf[idx] = f2bu(o);
          } else {  // G_FFN2
            Yf[idx] = v + bias[col] + bfu(resb[idx]);
          }
        }
      }
    }
  }
#undef STAGE
#undef STAGET
#undef LDA
#undef LDB
}

extern "C" void kernel_launch(void* const* d_in, const int* in_sizes, int n_in,
                              void* d_out, int out_size, void* d_ws, size_t ws_size,
                              hipStream_t stream) {
  const float* x  = (const float*)d_in[0];
  const float* wq = (const float*)d_in[1];
  const float* wk = (const float*)d_in[2];
  const float* wv = (const float*)d_in[3];
  const float* wo = (const float*)d_in[4];
  const float* w1 = (const float*)d_in[5];
  const float* b1 = (const float*)d_in[6];
  const float* w2 = (const float*)d_in[7];
  const float* b2 = (const float*)d_in[8];
  float* out = (float*)d_out;

  // workspace carve-up: ~197 MB peak
  char* p = (char*)d_ws;
  auto take = [&](size_t bytes) {
    char* r = p; p += (bytes + 255) & ~(size_t)255; return r;
  };
  u16*   xb   = (u16*)take((size_t)Mm * Dd * 2);    // x bf16; later attn bf16
  u16*   wkT  = (u16*)take((size_t)DIi * Dd * 2);
  u16*   wqT  = (u16*)take((size_t)DIi * Dd * 2);
  u16*   wvT  = (u16*)take((size_t)DIi * Dd * 2);
  u16*   woT  = (u16*)take((size_t)Dd * DIi * 2);
  u16*   w1T  = (u16*)take((size_t)DIi * Dd * 2);
  u16*   w2T  = (u16*)take((size_t)Dd * DIi * 2);
  u16*   wob  = (u16*)take((size_t)Bb * Dd * DIi * 2);  // 16.8 MB
  u16*   buf1 = (u16*)take((size_t)Mm * DIi * 2);   // P, then Q, then h
  float* nksq = (float*)take((size_t)Mm * 4);       // contiguous with next two
  float* nqsq = (float*)take((size_t)Mm * 4);
  float* kvp  = (float*)take((size_t)Bb * DIi * 4);
  (void)ws_size; (void)in_sizes; (void)n_in; (void)out_size;

  const dim3 tpB(32, 8);

  zero_f32<<<(2 * Mm + Bb * DIi + 255) / 256, 256, 0, stream>>>(nksq, 2 * Mm + Bb * DIi);

  f32_to_bf16_vec<<<2048, 256, 0, stream>>>(x, xb, (long)Mm * Dd / 4);
  transpose_f32_bf16_z<<<dim3(DIi / 32, Dd / 32, 4), tpB, 0, stream>>>(
      wk, wq, wv, w1, wkT, wqT, wvT, w1T, Dd, DIi);
  transpose_f32_bf16_z<<<dim3(Dd / 32, DIi / 32, 2), tpB, 0, stream>>>(
      wo, w2, wo, w2, woT, w2T, woT, w2T, DIi, Dd);

  // P = bf16(K ⊙ V) -> buf1, nksq atomics (fused dual-B GEMM, BM=128)
  kvp_gemm<<<dim3(DIi / 256, Mm / 128), 512, 0, stream>>>(xb, wkT, wvT, buf1, nksq);

  // kv[b,e] = sum_s P * rsqrt(nksq)
  kv_reduce<<<dim3(DIi / 1024, Bb, Ss / 256), 256, 0, stream>>>(buf1, nksq, kvp);

  // Q = x@wq -> buf1 (P dead) + nqsq
  gemm8<G_PROJ><<<dim3(DIi / 256, Mm / 256), 512, 0, stream>>>(
      xb, wqT, DIi, Dd, buf1, nullptr, nullptr, nullptr, nqsq, nullptr);

  // wob[b] = woT * kv[b]
  build_wob<<<dim3((Dd * DIi / 8 + 255) / 256, Bb), 256, 0, stream>>>(woT, kvp, wob);

  // attn = (q @ wob[b]) * rsqrt(nqsq) + xb -> bf16 in place of xb
  gemm8<G_WO><<<dim3(Dd / 256, Mm / 256), 512, 0, stream>>>(
      buf1, wob, Dd, DIi, xb, nullptr, xb, nullptr, nullptr, nqsq);

  // h = relu(attn @ w1 + b1) -> buf1
  gemm8<G_FFN1><<<dim3(DIi / 256, Mm / 256), 512, 0, stream>>>(
      xb, w1T, DIi, Dd, buf1, nullptr, nullptr, b1, nullptr, nullptr);

  // out = h @ w2 + b2 + attn
  gemm8<G_FFN2><<<dim3(Dd / 256, Mm / 256), 512, 0, stream>>>(
      buf1, w2T, Dd, DIi, nullptr, out, xb, b2, nullptr, nullptr);
}

// Round 9
// 601.040 us; speedup vs baseline: 1.1401x; 1.1401x over previous
//
#include <hip/hip_runtime.h>
#include <stdint.h>

// Problem constants
#define Bb  8
#define Ss  4096
#define Dd  512
#define DIi 2048
#define Mm  (Bb*Ss)   // 32768 rows

typedef unsigned short u16;
typedef __bf16 bf16x8 __attribute__((ext_vector_type(8)));
typedef float  f32x4  __attribute__((ext_vector_type(4)));

__device__ __forceinline__ float bfu(unsigned int u) {
  return __uint_as_float((u & 0xffffu) << 16);
}
__device__ __forceinline__ u16 f2bu(float f) {
  unsigned int x = __float_as_uint(f);
  return (u16)((x + 0x7fffu + ((x >> 16) & 1u)) >> 16);  // RNE
}

// ================= fused prep: zero + f32->bf16 conv + 6 transposes =================
// block ranges: [0,320) zero 81920 f32 | [320,2368) conv x->xb (grid-stride)
// [2368,+1024) wk | +1024 wq | +1024 wv | +1024 w1  (K=512,N=2048)
// then +1024 wo | +1024 w2                           (K=2048,N=512)
__device__ __forceinline__ void tr_tile(const float* __restrict__ W, u16* __restrict__ Wt,
                                        int K, int N, int local, int tid) {
  __shared__ float t[32][33];
  const int nx = N / 32;
  const int n0 = (local % nx) * 32, k0 = (local / nx) * 32;
  const int tx = tid & 31, ty = tid >> 5;   // 32 x 8
#pragma unroll
  for (int i = 0; i < 32; i += 8)
    t[ty + i][tx] = W[(long)(k0 + ty + i) * N + n0 + tx];
  __syncthreads();
#pragma unroll
  for (int i = 0; i < 32; i += 8)
    Wt[(long)(n0 + ty + i) * K + k0 + tx] = f2bu(t[tx][ty + i]);
}

__global__ __launch_bounds__(256) void prep(
    const float* __restrict__ x, u16* __restrict__ xb,
    const float* wk, const float* wq, const float* wv, const float* w1,
    const float* wo, const float* w2,
    u16* wkT, u16* wqT, u16* wvT, u16* w1T, u16* woT, u16* w2T,
    float* __restrict__ zptr) {
  const int bid = blockIdx.x, tid = threadIdx.x;
  if (bid < 320) {                       // zero 81920 floats (nksq,nqsq,kvp)
    zptr[bid * 256 + tid] = 0.f;
  } else if (bid < 2368) {               // conv x -> xb
    long i = (long)(bid - 320) * 256 + tid;
    const long n4 = (long)Mm * Dd / 4;
    const long st = 2048L * 256;
    for (; i < n4; i += st) {
      float4 v = ((const float4*)x)[i];
      ushort4 o;
      o.x = f2bu(v.x); o.y = f2bu(v.y); o.z = f2bu(v.z); o.w = f2bu(v.w);
      ((ushort4*)xb)[i] = o;
    }
  } else if (bid < 3392)  tr_tile(wk, wkT, Dd, DIi, bid - 2368, tid);
  else if (bid < 4416)    tr_tile(wq, wqT, Dd, DIi, bid - 3392, tid);
  else if (bid < 5440)    tr_tile(wv, wvT, Dd, DIi, bid - 4416, tid);
  else if (bid < 6464)    tr_tile(w1, w1T, Dd, DIi, bid - 5440, tid);
  else if (bid < 7488)    tr_tile(wo, woT, DIi, Dd, bid - 6464, tid);
  else                    tr_tile(w2, w2T, DIi, Dd, bid - 7488, tid);
}

// wob[b][n][k] = woT[n][k] * kv[b][k]   (bf16 out, 8 batch copies of wo^T)
__global__ __launch_bounds__(256) void build_wob(const u16* __restrict__ woT,
                                                 const float* __restrict__ kv,
                                                 u16* __restrict__ wob) {
  const int b = blockIdx.y;
  long i = (long)blockIdx.x * 256 + threadIdx.x;
  const long tot = (long)Dd * DIi / 8;
  if (i >= tot) return;
  const long e = i * 8;
  const int k = (int)(e & (DIi - 1));
  ushort4 w0 = *(const ushort4*)(woT + e);
  ushort4 w1 = *(const ushort4*)(woT + e + 4);
  const float* kvp = kv + (long)b * DIi + k;
  ushort4 o0, o1;
  o0.x = f2bu(bfu(w0.x) * kvp[0]); o0.y = f2bu(bfu(w0.y) * kvp[1]);
  o0.z = f2bu(bfu(w0.z) * kvp[2]); o0.w = f2bu(bfu(w0.w) * kvp[3]);
  o1.x = f2bu(bfu(w1.x) * kvp[4]); o1.y = f2bu(bfu(w1.y) * kvp[5]);
  o1.z = f2bu(bfu(w1.z) * kvp[6]); o1.w = f2bu(bfu(w1.w) * kvp[7]);
  u16* dst = wob + (long)b * Dd * DIi + e;
  *(ushort4*)dst = o0;
  *(ushort4*)(dst + 4) = o1;
}

#define GLL(src, dst) \
  __builtin_amdgcn_global_load_lds((const __attribute__((address_space(1))) unsigned int*)(src), \
                                   (__attribute__((address_space(3))) unsigned int*)(dst), 16, 0, 0)

// =================== 256^2-tile 8-wave pipelined GEMM (round-5 schedule) ===================
// G_PROJ: dual-target — row-half selects {wkT->YK,nsqK} vs {wqT->YQ,nsqQ}.
// G_KV: after main loop (acc = V tile), re-stage 256x256 stored-K tile into
// the freed 128 KB LDS (XOR-swizzled both sides), fold 1/||k||, atomicAdd kv.
enum { G_PROJ = 0, G_WO = 1, G_FFN1 = 2, G_FFN2 = 3, G_KV = 4 };

template<int MODE>
__global__ __launch_bounds__(512, 2) void gemm8(
    const u16* __restrict__ A, const u16* __restrict__ Bt, const u16* __restrict__ Bt2,
    int N, int K,
    u16* __restrict__ Ybf, u16* __restrict__ Ybf2, float* __restrict__ Yf,
    const u16* __restrict__ resb, const float* __restrict__ bias,
    float* __restrict__ nsq, float* __restrict__ nsq2, const float* __restrict__ nsqIn,
    const u16* __restrict__ Kst, float* __restrict__ kvout, int yoff)
{
  __shared__ u16 lds8[65536];   // 128 KB

  const int bx = blockIdx.x;
  const int by = blockIdx.y;
  const int tid  = threadIdx.x;
  const int lane = tid & 63;
  const int wid  = tid >> 6;
  const int wr = wid >> 2, wc = wid & 3;
  const int l15 = lane & 15, lg = lane >> 4;

  const long bm0l = (long)(by + yoff) * 256;          // logical panel
  const bool isQ = (MODE == G_PROJ) && (bm0l >= Mm);
  const long bm0 = isQ ? (bm0l - Mm) : bm0l;          // row in [0, Mm)
  const long bn0 = (long)bx * 256;
  const int NT = K >> 6;

  const int bq = (int)(bm0 >> 12);
  const u16* pA = A + bm0 * K;
  const u16* pB = (isQ ? Bt2 : Bt) + bn0 * K + (MODE == G_WO ? (size_t)bq * Dd * DIi : 0);

  const int rowT = ((tid >> 6) << 3) | (tid & 7);
  const int cc8  = ((tid >> 3) & 7) * 8;

#define STAGE(PTR, LD, H, TT, BUFU, REGU) do {                                  \
    const u16* s0_ = (PTR) + (size_t)((H) * 128 + rowT) * (LD)                  \
                     + (size_t)(TT) * 64 + cc8;                                 \
    u16* d_ = lds8 + (BUFU) + (REGU) + (H) * 8192 + wid * 512;                  \
    GLL(s0_, d_);                                                               \
    GLL(s0_ + (size_t)64 * (LD), d_ + 4096);                                    \
  } while (0)

  const int aoff = (wr * 16384 + (l15 >> 3) * 1024 + lg * 128 + (l15 & 7) * 16) >> 1;
  const int boff = (32768 + (wc >> 1) * 16384 + (wc & 1) * 8192 +
                    (l15 >> 3) * 1024 + lg * 128 + (l15 & 7) * 16) >> 1;
#define LDA(M_, KS_, BU_) (*(const bf16x8*)(lds8 + (BU_) + aoff + (M_) * 1024 + (KS_) * 256))
#define LDB(N_, KS_, BU_) (*(const bf16x8*)(lds8 + (BU_) + boff + (N_) * 1024 + (KS_) * 256))

  f32x4 acc[8][4] = {};

  // prologue: tile 0 (4 halves) + tile 1 A-half0
  STAGE(pA, K, 0, 0, 0, 0);
  STAGE(pA, K, 1, 0, 0, 0);
  STAGE(pB, K, 0, 0, 0, 16384);
  STAGE(pB, K, 1, 0, 0, 16384);
  STAGE(pA, K, 0, 1, 32768, 0);
  asm volatile("s_waitcnt vmcnt(2)" ::: "memory");
  __builtin_amdgcn_s_barrier();

  for (int t = 0; t < NT; ++t) {
    const int bufu = (t & 1) * 32768;
    const int nbuf = bufu ^ 32768;
    bf16x8 aF[4], bF[4];

    // phase 0: B ks0 + A(m0-3) ks0 ; stage H[t+1, A half1]
#pragma unroll
    for (int n = 0; n < 4; ++n) bF[n] = LDB(n, 0, bufu);
#pragma unroll
    for (int m = 0; m < 4; ++m) aF[m] = LDA(m, 0, bufu);
    if (t + 1 < NT) STAGE(pA, K, 1, t + 1, nbuf, 0);
    __builtin_amdgcn_s_barrier();
    __builtin_amdgcn_s_setprio(1);
#pragma unroll
    for (int m = 0; m < 4; ++m)
#pragma unroll
      for (int n = 0; n < 4; ++n)
        acc[m][n] = __builtin_amdgcn_mfma_f32_16x16x32_bf16(aF[m], bF[n], acc[m][n], 0, 0, 0);
    __builtin_amdgcn_s_setprio(0);

    // phase 1: A(m4-7) ks0 ; stage H[t+1, B half0]
#pragma unroll
    for (int m = 0; m < 4; ++m) aF[m] = LDA(4 + m, 0, bufu);
    if (t + 1 < NT) STAGE(pB, K, 0, t + 1, nbuf, 16384);
    __builtin_amdgcn_s_barrier();
    __builtin_amdgcn_s_setprio(1);
#pragma unroll
    for (int m = 0; m < 4; ++m)
#pragma unroll
      for (int n = 0; n < 4; ++n)
        acc[4 + m][n] = __builtin_amdgcn_mfma_f32_16x16x32_bf16(aF[m], bF[n], acc[4 + m][n], 0, 0, 0);
    __builtin_amdgcn_s_setprio(0);

    // phase 2: B ks1 + A(m0-3) ks1 ; stage H[t+1, B half1]
#pragma unroll
    for (int n = 0; n < 4; ++n) bF[n] = LDB(n, 1, bufu);
#pragma unroll
    for (int m = 0; m < 4; ++m) aF[m] = LDA(m, 1, bufu);
    if (t + 1 < NT) STAGE(pB, K, 1, t + 1, nbuf, 16384);
    __builtin_amdgcn_s_barrier();
    __builtin_amdgcn_s_setprio(1);
#pragma unroll
    for (int m = 0; m < 4; ++m)
#pragma unroll
      for (int n = 0; n < 4; ++n)
        acc[m][n] = __builtin_amdgcn_mfma_f32_16x16x32_bf16(aF[m], bF[n], acc[m][n], 0, 0, 0);
    __builtin_amdgcn_s_setprio(0);

    // phase 3: A(m4-7) ks1
#pragma unroll
    for (int m = 0; m < 4; ++m) aF[m] = LDA(4 + m, 1, bufu);
    __builtin_amdgcn_s_barrier();
    __builtin_amdgcn_s_setprio(1);
#pragma unroll
    for (int m = 0; m < 4; ++m)
#pragma unroll
      for (int n = 0; n < 4; ++n)
        acc[4 + m][n] = __builtin_amdgcn_mfma_f32_16x16x32_bf16(aF[m], bF[n], acc[4 + m][n], 0, 0, 0);
    __builtin_amdgcn_s_setprio(0);

    // tile boundary
    if (t + 1 < NT) {
      __builtin_amdgcn_s_barrier();
      if (t + 2 < NT) {
        STAGE(pA, K, 0, t + 2, bufu, 0);
        asm volatile("s_waitcnt vmcnt(2)" ::: "memory");
      } else {
        asm volatile("s_waitcnt vmcnt(0)" ::: "memory");
      }
      __builtin_amdgcn_s_barrier();
    }
  }

  // =================== epilogue ===================
  if constexpr (MODE == G_KV) {
    // acc = V tile. Re-stage 256x256 K-tile into lds8 (128 KB), XOR-swizzled.
    __syncthreads();
#pragma unroll
    for (int i = 0; i < 16; ++i) {
      const int r_ = i * 16 + wid * 2 + (lane >> 5);
      const int c_ = (lane & 31) ^ (r_ & 15);
      const u16* src = Kst + (size_t)(bm0 + r_) * N + bn0 + c_ * 8;
      u16* d_ = lds8 + i * 4096 + wid * 512;
      GLL(src, d_);
    }
    asm volatile("s_waitcnt vmcnt(0)" ::: "memory");
    __builtin_amdgcn_s_barrier();

    const int col4 = wc * 64 + l15;
    float cs[4] = {0.f, 0.f, 0.f, 0.f};
#pragma unroll
    for (int m = 0; m < 8; ++m) {
      const long row0g = bm0 + wr * 128 + m * 16 + lg * 4;
      float rn4[4];
#pragma unroll
      for (int r = 0; r < 4; ++r)
        rn4[r] = 1.f / fmaxf(sqrtf(nsqIn[row0g + r]), 1e-12f);
#pragma unroll
      for (int n = 0; n < 4; ++n) {
        const int col = col4 + n * 16;
#pragma unroll
        for (int r = 0; r < 4; ++r) {
          const int krow = wr * 128 + m * 16 + lg * 4 + r;
          const int byte_ = krow * 512 + (((col >> 3) ^ (krow & 15)) << 4) + (col & 7) * 2;
          const float kvl = bfu(*(const u16*)((const char*)lds8 + byte_));
          cs[n] += kvl * rn4[r] * acc[m][n][r];
        }
      }
    }
#pragma unroll
    for (int n = 0; n < 4; ++n) {
      cs[n] += __shfl_xor(cs[n], 16, 64);
      cs[n] += __shfl_xor(cs[n], 32, 64);
    }
    if (lane < 16) {
#pragma unroll
      for (int n = 0; n < 4; ++n) {
        const long col = bn0 + wc * 64 + n * 16 + l15;
        atomicAdd(&kvout[(long)bq * DIi + col], cs[n]);
      }
    }
  } else if constexpr (MODE == G_PROJ) {
    u16* Yo  = isQ ? Ybf2 : Ybf;
    float* ns = isQ ? nsq2 : nsq;
    float sk[32];
#pragma unroll
    for (int i = 0; i < 32; ++i) sk[i] = 0.f;
#pragma unroll
    for (int m = 0; m < 8; ++m) {
      const long row0 = bm0 + wr * 128 + m * 16 + lg * 4;
#pragma unroll
      for (int n = 0; n < 4; ++n) {
        const long col = bn0 + wc * 64 + n * 16 + l15;
#pragma unroll
        for (int r = 0; r < 4; ++r) {
          const float v = acc[m][n][r];
          Yo[(row0 + r) * N + col] = f2bu(v);
          sk[m * 4 + r] += v * v;
        }
      }
    }
#pragma unroll
    for (int i = 0; i < 32; ++i) {
#pragma unroll
      for (int off = 1; off < 16; off <<= 1)
        sk[i] += __shfl_xor(sk[i], off, 64);
    }
    if (l15 == 0) {
#pragma unroll
      for (int m = 0; m < 8; ++m)
#pragma unroll
        for (int r = 0; r < 4; ++r)
          atomicAdd(&ns[bm0 + wr * 128 + m * 16 + lg * 4 + r], sk[m * 4 + r]);
    }
  } else {
#pragma unroll
    for (int m = 0; m < 8; ++m) {
      const long row0 = bm0 + wr * 128 + m * 16 + lg * 4;
      float rq[4];
      if constexpr (MODE == G_WO) {
#pragma unroll
        for (int r = 0; r < 4; ++r)
          rq[r] = 1.f / fmaxf(sqrtf(nsqIn[row0 + r]), 1e-12f);
      }
#pragma unroll
      for (int n = 0; n < 4; ++n) {
        const long col = bn0 + wc * 64 + n * 16 + l15;
#pragma unroll
        for (int r = 0; r < 4; ++r) {
          const long idx = (row0 + r) * N + col;
          const float v = acc[m][n][r];
          if constexpr (MODE == G_WO) {
            Ybf[idx] = f2bu(v * rq[r] + bfu(resb[idx]));   // resb == Ybf, same idx
          } else if constexpr (MODE == G_FFN1) {
            float o = v + bias[col];
            o = o > 0.f ? o : 0.f;
            Ybf[idx] = f2bu(o);
          } else {  // G_FFN2
            Yf[idx] = v + bias[col] + bfu(resb[idx]);
          }
        }
      }
    }
  }
#undef STAGE
#undef LDA
#undef LDB
}

extern "C" void kernel_launch(void* const* d_in, const int* in_sizes, int n_in,
                              void* d_out, int out_size, void* d_ws, size_t ws_size,
                              hipStream_t stream) {
  const float* x  = (const float*)d_in[0];
  const float* wq = (const float*)d_in[1];
  const float* wk = (const float*)d_in[2];
  const float* wv = (const float*)d_in[3];
  const float* wo = (const float*)d_in[4];
  const float* w1 = (const float*)d_in[5];
  const float* b1 = (const float*)d_in[6];
  const float* w2 = (const float*)d_in[7];
  const float* b2 = (const float*)d_in[8];
  float* out = (float*)d_out;

  char* p = (char*)d_ws;
  auto take = [&](size_t bytes) {
    char* r = p; p += (bytes + 255) & ~(size_t)255; return r;
  };
  u16*   xb   = (u16*)take((size_t)Mm * Dd * 2);        // x bf16; later attn bf16
  u16*   wkT  = (u16*)take((size_t)DIi * Dd * 2);
  u16*   wqT  = (u16*)take((size_t)DIi * Dd * 2);
  u16*   wvT  = (u16*)take((size_t)DIi * Dd * 2);
  u16*   woT  = (u16*)take((size_t)Dd * DIi * 2);
  u16*   w1T  = (u16*)take((size_t)DIi * Dd * 2);
  u16*   w2T  = (u16*)take((size_t)Dd * DIi * 2);
  u16*   wob  = (u16*)take((size_t)Bb * Dd * DIi * 2);  // 16.8 MB
  u16*   buf1 = (u16*)take((size_t)Mm * DIi * 2);       // K (or K then Q), then h
  float* nksq = (float*)take((size_t)Mm * 4);           // contiguous with next two
  float* nqsq = (float*)take((size_t)Mm * 4);
  float* kvp  = (float*)take((size_t)Bb * DIi * 4);
  // optional parallel-Q buffer (134 MB) — only if workspace allows
  const size_t base_used = (size_t)(p - (char*)d_ws);
  const bool par = (ws_size >= base_used + (size_t)Mm * DIi * 2 + 4096);
  u16* bufQ = par ? (u16*)take((size_t)Mm * DIi * 2) : buf1;
  (void)in_sizes; (void)n_in; (void)out_size;

  // fused prep: zero(nksq..kvp) + conv + 6 transposes
  prep<<<8512, 256, 0, stream>>>(x, xb, wk, wq, wv, w1, wo, w2,
                                 wkT, wqT, wvT, w1T, woT, w2T, nksq);

  if (par) {
    // K->buf1 and Q->bufQ in ONE dispatch (independent, both read xb)
    gemm8<G_PROJ><<<dim3(DIi / 256, 2 * Mm / 256), 512, 0, stream>>>(
        xb, wkT, wqT, DIi, Dd, buf1, bufQ, nullptr, nullptr, nullptr,
        nksq, nqsq, nullptr, nullptr, nullptr, 0);
  } else {
    gemm8<G_PROJ><<<dim3(DIi / 256, Mm / 256), 512, 0, stream>>>(
        xb, wkT, wqT, DIi, Dd, buf1, nullptr, nullptr, nullptr, nullptr,
        nksq, nullptr, nullptr, nullptr, nullptr, 0);
  }

  // kv[b,e]: V = x@wv tiles + LDS-staged K re-read + 1/||k||  (K dead after)
  gemm8<G_KV><<<dim3(DIi / 256, Mm / 256), 512, 0, stream>>>(
      xb, wvT, nullptr, DIi, Dd, nullptr, nullptr, nullptr, nullptr, nullptr,
      nullptr, nullptr, nksq, buf1, kvp, 0);

  if (!par) {
    // sequential fallback: Q -> buf1 (K dead) + nqsq
    gemm8<G_PROJ><<<dim3(DIi / 256, Mm / 256), 512, 0, stream>>>(
        xb, wkT, wqT, DIi, Dd, nullptr, buf1, nullptr, nullptr, nullptr,
        nullptr, nqsq, nullptr, nullptr, nullptr, Mm / 256);
  }

  // wob[b] = woT * kv[b]
  build_wob<<<dim3((Dd * DIi / 8 + 255) / 256, Bb), 256, 0, stream>>>(woT, kvp, wob);

  // attn = (q @ wob[b]) * rsqrt(nqsq) + xb -> bf16 in place of xb
  gemm8<G_WO><<<dim3(Dd / 256, Mm / 256), 512, 0, stream>>>(
      bufQ, wob, nullptr, Dd, DIi, xb, nullptr, nullptr, xb, nullptr,
      nullptr, nullptr, nqsq, nullptr, nullptr, 0);

  // h = relu(attn @ w1 + b1) -> buf1
  gemm8<G_FFN1><<<dim3(DIi / 256, Mm / 256), 512, 0, stream>>>(
      xb, w1T, nullptr, DIi, Dd, buf1, nullptr, nullptr, nullptr, b1,
      nullptr, nullptr, nullptr, nullptr, nullptr, 0);

  // out = h @ w2 + b2 + attn
  gemm8<G_FFN2><<<dim3(Dd / 256, Mm / 256), 512, 0, stream>>>(
      buf1, w2T, nullptr, Dd, DIi, nullptr, nullptr, out, xb, b2,
      nullptr, nullptr, nullptr, nullptr, nullptr, 0);
}